// Round 6
// baseline (412.184 us; speedup 1.0000x reference)
//
#include <hip/hip_runtime.h>
#include <stdint.h>

#define IC   4096
#define BLK  256
#define CPT  4      // float4 chunks per thread: 4 * 4 * 256 = 4096 elems/row
#define RPB  4      // rows per block (strided by gridDim)

// ---- in-wave reductions (64 lanes), result broadcast to all lanes ----
__device__ __forceinline__ double wsum_d(double v) {
    #pragma unroll
    for (int off = 32; off; off >>= 1) v += __shfl_xor(v, off);
    return v;
}
__device__ __forceinline__ int wsum_i(int v) {
    #pragma unroll
    for (int off = 32; off; off >>= 1) v += __shfl_xor(v, off);
    return v;
}

// One row: 3 reduction rounds (disjoint LDS slots -> ONE barrier per round)
// + epilogue store. Numerics bit-matched to R5 (absmax 0.0) except
// mean/scale = sum * (1/dc) instead of sum/dc (<=1.5 ulp, sign-safe).
__device__ __forceinline__ void process_row(
    const float4 (&xf)[CPT], const uint32_t bm,
    float* __restrict__ orow,
    double* sm_d, int* sm_i,
    const int lane, const int wid, const int tid)
{
    // ---- round 1: masked sum (fp64, 4-way ILP) + popcount ----
    double a0 = 0.0, a1 = 0.0, a2 = 0.0, a3 = 0.0;
    #pragma unroll
    for (int i = 0; i < CPT; ++i) {
        a0 += (double)(((bm >> (4*i + 0)) & 1u) ? xf[i].x : 0.0f);
        a1 += (double)(((bm >> (4*i + 1)) & 1u) ? xf[i].y : 0.0f);
        a2 += (double)(((bm >> (4*i + 2)) & 1u) ? xf[i].z : 0.0f);
        a3 += (double)(((bm >> (4*i + 3)) & 1u) ? xf[i].w : 0.0f);
    }
    {
        double sw = wsum_d((a0 + a1) + (a2 + a3));
        int    cw = wsum_i(__popc(bm));
        if (lane == 0) { sm_d[wid] = sw; sm_i[wid] = cw; }
    }
    __syncthreads();
    const double s   = (sm_d[0] + sm_d[1]) + (sm_d[2] + sm_d[3]);
    const int    cnt = (sm_i[0] + sm_i[1]) + (sm_i[2] + sm_i[3]);

    const bool   has   = (cnt > 0);
    const double dc    = (double)(has ? cnt : 1);
    const double inv   = 1.0 / dc;            // the ONLY fp64 divide per row
    const double mean1 = has ? s * inv : 0.0;

    // ---- round 2: sa = sum |x-mean1| (masked), pn = sum sign(x-mean1) ----
    double p0 = 0.0, p1 = 0.0, p2 = 0.0, p3 = 0.0;
    int q = 0;
    #pragma unroll
    for (int i = 0; i < CPT; ++i) {
        const float e[4] = {xf[i].x, xf[i].y, xf[i].z, xf[i].w};
        {
            const bool b = (bm >> (4*i + 0)) & 1u;
            const double ce = (double)e[0] - mean1;
            p0 += b ? fabs(ce) : 0.0;
            q  += b ? (int)(ce > 0.0) - (int)(ce < 0.0) : 0;
        }
        {
            const bool b = (bm >> (4*i + 1)) & 1u;
            const double ce = (double)e[1] - mean1;
            p1 += b ? fabs(ce) : 0.0;
            q  += b ? (int)(ce > 0.0) - (int)(ce < 0.0) : 0;
        }
        {
            const bool b = (bm >> (4*i + 2)) & 1u;
            const double ce = (double)e[2] - mean1;
            p2 += b ? fabs(ce) : 0.0;
            q  += b ? (int)(ce > 0.0) - (int)(ce < 0.0) : 0;
        }
        {
            const bool b = (bm >> (4*i + 3)) & 1u;
            const double ce = (double)e[3] - mean1;
            p3 += b ? fabs(ce) : 0.0;
            q  += b ? (int)(ce > 0.0) - (int)(ce < 0.0) : 0;
        }
    }
    {
        double sw = wsum_d((p0 + p1) + (p2 + p3));
        int    qw = wsum_i(q);
        if (lane == 0) { sm_d[4 + wid] = sw; sm_i[4 + wid] = qw; }
    }
    __syncthreads();
    const double sa = (sm_d[4] + sm_d[5]) + (sm_d[6] + sm_d[7]);
    const int    pn = (sm_i[4] + sm_i[5]) + (sm_i[6] + sm_i[7]);

    const double scale1 = has ? sa * inv : 0.0;
    // analytic mean2: sum(r2) = (s - dc*mean1) - scale1*pn (HW-validated R4/R5)
    const double s2    = (s - dc * mean1) - scale1 * (double)pn;
    const double mean2 = has ? s2 * inv : 0.0;

    const double Ap = scale1 + mean1;
    const double Am = -scale1 + mean1;
    const double A0 = mean1;

    // ---- round 3: sd = sum |(x - b1) - mean2| (masked) ----
    double d0 = 0.0, d1 = 0.0, d2 = 0.0, d3 = 0.0;
    #pragma unroll
    for (int i = 0; i < CPT; ++i) {
        const float e[4] = {xf[i].x, xf[i].y, xf[i].z, xf[i].w};
        {
            const bool b = (bm >> (4*i + 0)) & 1u;
            const double xd = (double)e[0];
            const double A  = (xd > mean1) ? Ap : ((xd < mean1) ? Am : A0);
            const double c2 = (xd - A) - mean2;   // ref-exact rounding chain
            d0 += b ? fabs(c2) : 0.0;
        }
        {
            const bool b = (bm >> (4*i + 1)) & 1u;
            const double xd = (double)e[1];
            const double A  = (xd > mean1) ? Ap : ((xd < mean1) ? Am : A0);
            const double c2 = (xd - A) - mean2;
            d1 += b ? fabs(c2) : 0.0;
        }
        {
            const bool b = (bm >> (4*i + 2)) & 1u;
            const double xd = (double)e[2];
            const double A  = (xd > mean1) ? Ap : ((xd < mean1) ? Am : A0);
            const double c2 = (xd - A) - mean2;
            d2 += b ? fabs(c2) : 0.0;
        }
        {
            const bool b = (bm >> (4*i + 3)) & 1u;
            const double xd = (double)e[3];
            const double A  = (xd > mean1) ? Ap : ((xd < mean1) ? Am : A0);
            const double c2 = (xd - A) - mean2;
            d3 += b ? fabs(c2) : 0.0;
        }
    }
    {
        double sw = wsum_d((d0 + d1) + (d2 + d3));
        if (lane == 0) sm_d[8 + wid] = sw;
    }
    __syncthreads();
    const double sd = (sm_d[8] + sm_d[9]) + (sm_d[10] + sm_d[11]);

    const double scale2 = has ? sd * inv : 0.0;
    const double Bp = scale2 + mean2;
    const double Bm = -scale2 + mean2;
    const double B0 = mean2;

    // ---- epilogue: out = (b1 + b2) on mask, 0 elsewhere ----
    #pragma unroll
    for (int i = 0; i < CPT; ++i) {
        const float e[4] = {xf[i].x, xf[i].y, xf[i].z, xf[i].w};
        float4 o;
        float* op = &o.x;
        #pragma unroll
        for (int k = 0; k < 4; ++k) {
            const bool b = (bm >> (4*i + k)) & 1u;
            const double xd = (double)e[k];
            const double A  = (xd > mean1) ? Ap : ((xd < mean1) ? Am : A0);
            const double c2 = (xd - A) - mean2;
            const double B  = (c2 > 0.0) ? Bp : ((c2 < 0.0) ? Bm : B0);
            const float  r  = (float)(A + B);
            op[k] = b ? r : 0.0f;
        }
        ((float4*)orow)[i * BLK + tid] = o;
    }
}

__global__ __launch_bounds__(BLK) void binarize_kernel(
    const float* __restrict__ x,
    const uint8_t* __restrict__ mask,
    float* __restrict__ out,
    const int rows)
{
    __shared__ double sm_d[12];
    __shared__ int    sm_i[8];

    const int tid  = threadIdx.x;
    const int lane = tid & 63;
    const int wid  = tid >> 6;
    const int G    = gridDim.x;

    // ---- mask dtype detection, once per block ----
    const uint32_t probe = ((const uint32_t*)mask)[lane];
    const bool mask_is_bytes = __any(probe > 1u);

    int row = blockIdx.x;

    if (mask_is_bytes) {
        // initial load (row < gridDim <= rows always)
        float4   xc[CPT];
        uint32_t mc[CPT];
        {
            const float4*   xp = (const float4*)(x + (size_t)row * IC);
            const uint32_t* mp = (const uint32_t*)(mask + (size_t)row * IC);
            #pragma unroll
            for (int i = 0; i < CPT; ++i) { xc[i] = xp[i*BLK + tid]; mc[i] = mp[i*BLK + tid]; }
        }
        for (int it = 0; it < RPB && row < rows; ++it) {
            const int nrow = row + G;
            float4   xn[CPT];
            uint32_t mn[CPT];
            if (nrow < rows) {      // prefetch next row: flies under reductions
                const float4*   xp = (const float4*)(x + (size_t)nrow * IC);
                const uint32_t* mp = (const uint32_t*)(mask + (size_t)nrow * IC);
                #pragma unroll
                for (int i = 0; i < CPT; ++i) { xn[i] = xp[i*BLK + tid]; mn[i] = mp[i*BLK + tid]; }
            }
            uint32_t bm = 0;
            #pragma unroll
            for (int i = 0; i < CPT; ++i)       // bytes(0/1)x4 -> 4 bits
                bm |= (((mc[i] * 0x01020408u) >> 24) & 0xFu) << (4 * i);

            process_row(xc, bm, out + (size_t)row * IC, sm_d, sm_i, lane, wid, tid);

            #pragma unroll
            for (int i = 0; i < CPT; ++i) { xc[i] = xn[i]; mc[i] = mn[i]; }
            row = nrow;
        }
    } else {
        // int32 0/1 mask path: prefetch x only (int4 mask regs too costly)
        float4 xc[CPT];
        {
            const float4* xp = (const float4*)(x + (size_t)row * IC);
            #pragma unroll
            for (int i = 0; i < CPT; ++i) xc[i] = xp[i*BLK + tid];
        }
        for (int it = 0; it < RPB && row < rows; ++it) {
            const int nrow = row + G;
            float4 xn[CPT];
            if (nrow < rows) {
                const float4* xp = (const float4*)(x + (size_t)nrow * IC);
                #pragma unroll
                for (int i = 0; i < CPT; ++i) xn[i] = xp[i*BLK + tid];
            }
            uint32_t bm = 0;
            {
                const int4* mq = (const int4*)mask + (size_t)row * (IC / 4);
                #pragma unroll
                for (int i = 0; i < CPT; ++i) {
                    int4 m4 = mq[i*BLK + tid];
                    uint32_t b = (m4.x ? 1u : 0u) | (m4.y ? 2u : 0u)
                               | (m4.z ? 4u : 0u) | (m4.w ? 8u : 0u);
                    bm |= b << (4 * i);
                }
            }
            process_row(xc, bm, out + (size_t)row * IC, sm_d, sm_i, lane, wid, tid);

            #pragma unroll
            for (int i = 0; i < CPT; ++i) xc[i] = xn[i];
            row = nrow;
        }
    }
}

extern "C" void kernel_launch(void* const* d_in, const int* in_sizes, int n_in,
                              void* d_out, int out_size, void* d_ws, size_t ws_size,
                              hipStream_t stream) {
    const float*   x    = (const float*)d_in[0];
    const uint8_t* mask = (const uint8_t*)d_in[1];
    float*         out  = (float*)d_out;

    const int rows = in_sizes[0] / IC;             // 11008
    const int grid = (rows + RPB - 1) / RPB;       // 2752
    binarize_kernel<<<grid, BLK, 0, stream>>>(x, mask, out, rows);
}